// Round 16
// baseline (676.908 us; speedup 1.0000x reference)
//
#include <hip/hip_runtime.h>
#include <hip/hip_bf16.h>
#include <cstdint>
#include <cstddef>

#define B_    512
#define HW_   196
#define ENC_  2048
#define DEC_  512
#define ATTN_ 512
#define M_    (B_*HW_)   // 100352 = 392*256

typedef __attribute__((ext_vector_type(8)))  short short8;
typedef __attribute__((ext_vector_type(4)))  float f32x4;
typedef __attribute__((ext_vector_type(16))) float f32x16;

__device__ __forceinline__ unsigned short f2bf(float x) {
  __bf16 b = (__bf16)x;
  return __builtin_bit_cast(unsigned short, b);
}
__device__ __forceinline__ unsigned int cvt2(float x, float y) {
  return (unsigned)f2bf(x) | ((unsigned)f2bf(y) << 16);
}

__device__ __forceinline__ void gload_lds16(const void* g, void* l) {
  __builtin_amdgcn_global_load_lds(
      (const __attribute__((address_space(1))) void*)g,
      (__attribute__((address_space(3))) void*)l, 16, 0, 0);
}

// ---------------- kernel 0 (fused preamble): convert | transpose | attn2
#define NCONV 2048
__global__ __launch_bounds__(256)
void k_pre(const float* __restrict__ enc, unsigned short* __restrict__ ench,
           const float* __restrict__ Wenc, unsigned short* __restrict__ WencT,
           const float* __restrict__ dec_h, const float* __restrict__ Wdec,
           const float* __restrict__ bdec, const float* __restrict__ benc,
           float* __restrict__ attn2p) {
  __shared__ float smem[32][33];
  const int bid = blockIdx.x;
  const int t   = threadIdx.x;
  if (bid < NCONV) {
    const size_t total  = (size_t)M_ * ENC_;
    const size_t stride = (size_t)NCONV * 256 * 8;
    for (size_t i = ((size_t)bid * 256 + t) * 8; i < total; i += stride) {
      const float4 a = *reinterpret_cast<const float4*>(enc + i);
      const float4 b = *reinterpret_cast<const float4*>(enc + i + 4);
      uint4 o;
      o.x = cvt2(a.x, a.y);  o.y = cvt2(a.z, a.w);
      o.z = cvt2(b.x, b.y);  o.w = cvt2(b.z, b.w);
      *reinterpret_cast<uint4*>(ench + i) = o;
    }
  } else if (bid < NCONV + 1024) {
    const int b2 = bid - NCONV;
    const int e0 = (b2 & 63) * 32;
    const int a0 = (b2 >> 6) * 32;
    const int li = t >> 5;
    const int lj = t & 31;
    #pragma unroll
    for (int rep = 0; rep < 4; ++rep) {
      const int i = li + rep*8;
      smem[i][lj] = Wenc[(size_t)(e0 + i)*ATTN_ + a0 + lj];
    }
    __syncthreads();
    #pragma unroll
    for (int rep = 0; rep < 4; ++rep) {
      const int ar = li + rep*8;
      WencT[(size_t)(a0 + ar)*ENC_ + e0 + lj] = f2bf(smem[lj][ar]);
    }
  } else {
    const int b = bid - (NCONV + 1024);
    float* dh = &smem[0][0];
    dh[t]       = dec_h[b*DEC_ + t];
    dh[t + 256] = dec_h[b*DEC_ + t + 256];
    __syncthreads();
    #pragma unroll
    for (int rep = 0; rep < 2; ++rep) {
      const int a = t + rep*256;
      float acc = bdec[a] + benc[a];
      #pragma unroll 8
      for (int k = 0; k < DEC_; ++k)
        acc = fmaf(dh[k], Wdec[(size_t)k*ATTN_ + a], acc);
      attn2p[(size_t)b*ATTN_ + a] = acc;
    }
  }
}

// ---------------- standalone attn2 / transpose (fallback path only)
__global__ __launch_bounds__(256)
void k_attn2(const float* __restrict__ dec_h, const float* __restrict__ Wdec,
             const float* __restrict__ bdec, const float* __restrict__ benc,
             float* __restrict__ attn2p) {
  __shared__ float dh[DEC_];
  const int b = blockIdx.x;
  const int t = threadIdx.x;
  dh[t]       = dec_h[b*DEC_ + t];
  dh[t + 256] = dec_h[b*DEC_ + t + 256];
  __syncthreads();
  #pragma unroll
  for (int rep = 0; rep < 2; ++rep) {
    const int a = t + rep*256;
    float acc = bdec[a] + benc[a];
    #pragma unroll 8
    for (int k = 0; k < DEC_; ++k)
      acc = fmaf(dh[k], Wdec[(size_t)k*ATTN_ + a], acc);
    attn2p[(size_t)b*ATTN_ + a] = acc;
  }
}

__global__ __launch_bounds__(256)
void k_transpose(const float* __restrict__ Wenc, unsigned short* __restrict__ WencT) {
  __shared__ float tile[32][33];
  const int e0 = blockIdx.x * 32;
  const int a0 = blockIdx.y * 32;
  const int t  = threadIdx.x;
  const int li = t >> 5;
  const int lj = t & 31;
  #pragma unroll
  for (int rep = 0; rep < 4; ++rep) {
    const int i = li + rep*8;
    tile[i][lj] = Wenc[(size_t)(e0 + i)*ATTN_ + a0 + lj];
  }
  __syncthreads();
  #pragma unroll
  for (int rep = 0; rep < 4; ++rep) {
    const int ar = li + rep*8;
    WencT[(size_t)(a0 + ar)*ENC_ + e0 + lj] = f2bf(tile[lj][ar]);
  }
}

// ---------------- kernel 3: r11 schedule, 32x32x16 MFMA geometry
// BM=256 BN=128 BK=64, 512 thr (8 waves 4Mx2N), wave 64x64 = 2x2 of 32x32
// frags, acc 2x2 x f32x16. Tri-buffered LDS, ONE barrier + counted vmcnt(6)
// per K-tile. Per window (k-half): 8 b128 reads + 8 MFMA 32x32x16 (same FLOP
// as 16x 16x16x32, +15% rate, half the issue count).
// A/B frag: lane l -> row l&31, k = (l>>5)*8+j  (contiguous-8, gfx950 2xK).
#define NKT 32   // 2048/64

__global__ __launch_bounds__(512, 1)
void k_gemm8(const unsigned short* __restrict__ ench,
             const unsigned short* __restrict__ WencT,
             const float* __restrict__ attn2p,
             const float* __restrict__ Wv,
             float* __restrict__ partials) {
  __shared__ unsigned short A3[3][256*64];   // 96 KB
  __shared__ unsigned short B3[3][128*64];   // 48 KB

  const int tid = threadIdx.x;
  const int id  = blockIdx.x;
  const int xcd  = id & 7;
  const int rest = id >> 3;              // [0,196)
  const int nb   = rest & 3;
  const int mblk = (rest >> 2)*8 + xcd;  // [0,392) bijective
  const int r0 = mblk * 256;
  const int n0 = nb * 128;

  const int w  = tid >> 6;
  const int l  = tid & 63;
  const int wm = w >> 1, wn = w & 1;     // 4M x 2N
  const int l31 = l & 31;
  const int lh  = l >> 5;                // half 0/1

  // staging (unchanged from r11): pos p holds src chunk (p&7)^(row&7)
  const unsigned short* aBase[2];
  #pragma unroll
  for (int i = 0; i < 2; ++i) {
    const int j  = tid + i*512;
    const int rr = j >> 3;
    const int kc = (j & 7) ^ (rr & 7);
    aBase[i] = ench + (size_t)(r0 + rr)*ENC_ + kc*8;
  }
  const unsigned short* bBase;
  {
    const int rr = tid >> 3;
    const int kc = (tid & 7) ^ (rr & 7);
    bBase = WencT + (size_t)(n0 + rr)*ENC_ + kc*8;
  }

  // frag read offsets: window ks (k-half), sub kk -> ksub = ks*2+kk;
  // chunk c = ksub*2 + lh; row R; swizzled chunk = c ^ (R&7)
  int aOff[2][2][2], bOff[2][2][2];
  #pragma unroll
  for (int ks = 0; ks < 2; ++ks) {
    #pragma unroll
    for (int kk = 0; kk < 2; ++kk) {
      const int c = (ks*2 + kk)*2 + lh;
      #pragma unroll
      for (int mi = 0; mi < 2; ++mi) {
        const int R = wm*64 + mi*32 + l31;
        aOff[ks][mi][kk] = (R*8 + (c ^ (R & 7))) * 8;
      }
      #pragma unroll
      for (int ni = 0; ni < 2; ++ni) {
        const int C = wn*64 + ni*32 + l31;
        bOff[ks][ni][kk] = (C*8 + (c ^ (C & 7))) * 8;
      }
    }
  }

  f32x16 acc[2][2];
  #pragma unroll
  for (int mi = 0; mi < 2; ++mi)
    #pragma unroll
    for (int ni = 0; ni < 2; ++ni)
      #pragma unroll
      for (int r = 0; r < 16; ++r)
        acc[mi][ni][r] = 0.f;

#define STAGE(KT, KS) do {                                                     \
    const size_t _ko = (size_t)(KT)*64;                                        \
    const int _bw = (KT) % 3;                                                  \
    gload_lds16(aBase[0] + (size_t)(KS)*(128*ENC_) + _ko,                      \
                &A3[_bw][(KS)*8192 + tid*8]);                                  \
    gload_lds16(aBase[1] + (size_t)(KS)*(128*ENC_) + _ko,                      \
                &A3[_bw][(KS)*8192 + 4096 + tid*8]);                           \
    gload_lds16(bBase    + (size_t)(KS)*(64*ENC_)  + _ko,                      \
                &B3[_bw][(KS)*4096 + tid*8]);                                  \
  } while (0)

#define MFMA8(AA, BB) do {                                                     \
    _Pragma("unroll")                                                          \
    for (int kk = 0; kk < 2; ++kk)                                             \
      _Pragma("unroll")                                                        \
      for (int mi = 0; mi < 2; ++mi)                                           \
        _Pragma("unroll")                                                      \
        for (int ni = 0; ni < 2; ++ni)                                         \
          acc[mi][ni] = __builtin_amdgcn_mfma_f32_32x32x16_bf16(               \
              AA[mi][kk], BB[ni][kk], acc[mi][ni], 0, 0, 0);                   \
  } while (0)

#define PIN8 do {                                                              \
    _Pragma("unroll")                                                          \
    for (int g = 0; g < 4; ++g) {                                              \
      __builtin_amdgcn_sched_group_barrier(0x008, 2, 0);  /* 2 MFMA   */       \
      __builtin_amdgcn_sched_group_barrier(0x100, 2, 0);  /* 2 DS_READ*/       \
    }                                                                          \
  } while (0)

#define READSET(AD, BD, BUF, KS) do {                                          \
    const unsigned short* _aB = &A3[BUF][0];                                   \
    const unsigned short* _bB = &B3[BUF][0];                                   \
    _Pragma("unroll")                                                          \
    for (int mi = 0; mi < 2; ++mi)                                             \
      _Pragma("unroll")                                                        \
      for (int kk = 0; kk < 2; ++kk)                                           \
        AD[mi][kk] = *reinterpret_cast<const short8*>(&_aB[aOff[KS][mi][kk]]); \
    _Pragma("unroll")                                                          \
    for (int ni = 0; ni < 2; ++ni)                                             \
      _Pragma("unroll")                                                        \
      for (int kk = 0; kk < 2; ++kk)                                           \
        BD[ni][kk] = *reinterpret_cast<const short8*>(&_bB[bOff[KS][ni][kk]]); \
  } while (0)

  STAGE(0, 0); STAGE(0, 1);
  STAGE(1, 0); STAGE(1, 1);
  asm volatile("s_waitcnt vmcnt(6)" ::: "memory");
  __builtin_amdgcn_s_barrier();

  short8 aX[2][2], bX[2][2], aY[2][2], bY[2][2];
  READSET(aX, bX, 0, 0);

  for (int kt = 0; kt < 30; ++kt) {
    const int bc = kt % 3;
    const int bn = (kt + 1) % 3;
    asm volatile("s_waitcnt lgkmcnt(0)" ::: "memory");
    __builtin_amdgcn_sched_barrier(0);
    __builtin_amdgcn_s_setprio(1);
    READSET(aY, bY, bc, 1);
    MFMA8(aX, bX);
    PIN8;
    __builtin_amdgcn_s_setprio(0);
    __builtin_amdgcn_sched_barrier(0);
    STAGE(kt + 2, 0);
    STAGE(kt + 2, 1);
    __builtin_amdgcn_sched_barrier(0);
    asm volatile("s_waitcnt vmcnt(6)" ::: "memory");
    __builtin_amdgcn_s_barrier();
    asm volatile("s_waitcnt lgkmcnt(0)" ::: "memory");
    __builtin_amdgcn_sched_barrier(0);
    __builtin_amdgcn_s_setprio(1);
    READSET(aX, bX, bn, 0);
    MFMA8(aY, bY);
    PIN8;
    __builtin_amdgcn_s_setprio(0);
    __builtin_amdgcn_sched_barrier(0);
  }
  {
    asm volatile("s_waitcnt lgkmcnt(0)" ::: "memory");
    __builtin_amdgcn_sched_barrier(0);
    __builtin_amdgcn_s_setprio(1);
    READSET(aY, bY, 0, 1);          // (30,1), buf 0
    MFMA8(aX, bX);
    PIN8;
    __builtin_amdgcn_s_setprio(0);
    __builtin_amdgcn_sched_barrier(0);
    asm volatile("s_waitcnt vmcnt(0)" ::: "memory");
    __builtin_amdgcn_s_barrier();
    asm volatile("s_waitcnt lgkmcnt(0)" ::: "memory");
    __builtin_amdgcn_sched_barrier(0);
    __builtin_amdgcn_s_setprio(1);
    READSET(aX, bX, 1, 0);          // (31,0), buf 1
    MFMA8(aY, bY);
    PIN8;
    __builtin_amdgcn_s_setprio(0);
    __builtin_amdgcn_sched_barrier(0);
  }
  {
    asm volatile("s_waitcnt lgkmcnt(0)" ::: "memory");
    __builtin_amdgcn_sched_barrier(0);
    __builtin_amdgcn_s_setprio(1);
    READSET(aY, bY, 1, 1);          // (31,1)
    MFMA8(aX, bX);
    PIN8;
    __builtin_amdgcn_s_setprio(0);
    asm volatile("s_waitcnt lgkmcnt(0)" ::: "memory");
    __builtin_amdgcn_sched_barrier(0);
    MFMA8(aY, bY);
  }
#undef READSET
#undef PIN8
#undef MFMA8
#undef STAGE

  // ---- epilogue: relu(acc + attn2p) · W_v over this block's 128 cols
  // 32x32 C/D layout: col = l&31, row = (r&3) + 8*(r>>2) + 4*(l>>5)
  __syncthreads();
  float* plog = reinterpret_cast<float*>(&A3[0][0]);   // [256][2]
  float wvv[2];
  #pragma unroll
  for (int ni = 0; ni < 2; ++ni) wvv[ni] = Wv[n0 + wn*64 + ni*32 + l31];
  #pragma unroll
  for (int mi = 0; mi < 2; ++mi) {
    #pragma unroll
    for (int r = 0; r < 16; ++r) {
      const int row_local = wm*64 + mi*32 + (r & 3) + 8*(r >> 2) + 4*lh;
      const int bb = (r0 + row_local) / HW_;
      const float* a2 = attn2p + (size_t)bb*ATTN_ + n0 + wn*64 + l31;
      float s = 0.f;
      #pragma unroll
      for (int ni = 0; ni < 2; ++ni) {
        float v = acc[mi][ni][r] + a2[ni*32];
        v = fmaxf(v, 0.f);
        s = fmaf(v, wvv[ni], s);
      }
      s += __shfl_xor(s, 1);
      s += __shfl_xor(s, 2);
      s += __shfl_xor(s, 4);
      s += __shfl_xor(s, 8);
      s += __shfl_xor(s, 16);
      if (l31 == 0) plog[row_local*2 + wn] = s;
    }
  }
  __syncthreads();
  if (tid < 256)
    partials[(size_t)(r0 + tid)*4 + nb] = plog[tid*2] + plog[tid*2 + 1];
}

// ---------------- kernel 3 (fallback, small ws): f32 reg-staged 2-phase
#define BM 128
#define BN 128
#define BK 32
#define LDA 40
#define NT (ENC_/BK)
__device__ __forceinline__ int invswz8(int p) {
  const int b2 = ((p >> 2) ^ (p >> 4)) & 1;
  const int b1 = ((p >> 1) ^ (p >> 3)) & 1;
  const int b0 = (p ^ (p >> 2) ^ (p >> 4)) & 1;
  return (p & ~7) | (b2 << 2) | (b1 << 1) | b0;
}
__global__ __launch_bounds__(256)
void k_gemm_logits_f32(const float* __restrict__ enc,
                       const unsigned short* __restrict__ WencT,
                       const float* __restrict__ attn2p,
                       const float* __restrict__ Wv,
                       float* __restrict__ partials) {
  __shared__ unsigned short As[BM*LDA];
  __shared__ unsigned short Bs[2][BN*BK];
  __shared__ float plog[BM][2];
  const int tid  = threadIdx.x;
  const int id   = blockIdx.x;
  const int xcd  = id & 7;
  const int rest = id >> 3;
  const int nb   = rest & 3;
  const int mblk = (rest >> 2) * 8 + xcd;
  const int r0 = mblk * BM;
  const int n0 = nb * BN;
  const int arow  = tid >> 1;
  const int ahalf = (tid & 1) << 4;
  const float* aptr = enc + (size_t)(r0 + arow)*ENC_ + ahalf;
  const unsigned short* bbase = WencT + (size_t)n0*ENC_;
  const int w  = tid >> 6;
  const int l  = tid & 63;
  const int wm = w >> 1, wn = w & 1;
  const int lrow = l & 15;
  const int kg   = l >> 4;
  const int lk8  = kg << 3;
  const int g4   = kg << 2;
  f32x4 acc[4][4];
  #pragma unroll
  for (int mi = 0; mi < 4; ++mi)
    #pragma unroll
    for (int ni = 0; ni < 4; ++ni)
      acc[mi][ni] = (f32x4){0.f, 0.f, 0.f, 0.f};
  float4 ar[4];
  #pragma unroll
  for (int i = 0; i < 4; ++i) ar[i] = *reinterpret_cast<const float4*>(aptr + i*4);
  #pragma unroll
  for (int r = 0; r < 2; ++r) {
    const int p = r*256 + tid;
    const int c = invswz8(p);
    gload_lds16(bbase + (size_t)(c >> 2)*ENC_ + (c & 3)*8, &Bs[0][p*8]);
  }
  for (int kt = 0; kt < NT; ++kt) {
    {
      unsigned int pk[8];
      #pragma unroll
      for (int i = 0; i < 4; ++i) {
        pk[2*i]   = cvt2(ar[i].x, ar[i].y);
        pk[2*i+1] = cvt2(ar[i].z, ar[i].w);
      }
      uint4* da = reinterpret_cast<uint4*>(&As[arow*LDA + ahalf]);
      da[0] = make_uint4(pk[0], pk[1], pk[2], pk[3]);
      da[1] = make_uint4(pk[4], pk[5], pk[6], pk[7]);
    }
    __syncthreads();
    if (kt + 1 < NT) {
      const float* ap = aptr + (kt + 1)*BK;
      #pragma unroll
      for (int i = 0; i < 4; ++i) ar[i] = *reinterpret_cast<const float4*>(ap + i*4);
      const int k0n = (kt + 1)*BK;
      unsigned short* bdst = Bs[(kt + 1) & 1];
      #pragma unroll
      for (int r = 0; r < 2; ++r) {
        const int p = r*256 + tid;
        const int c = invswz8(p);
        gload_lds16(bbase + (size_t)(c >> 2)*ENC_ + k0n + (c & 3)*8, &bdst[p*8]);
      }
    }
    const unsigned short* bsc = Bs[kt & 1];
    short8 aF[4], bF[4];
    #pragma unroll
    for (int mi = 0; mi < 4; ++mi)
      aF[mi] = *reinterpret_cast<const short8*>(&As[(wm*64 + mi*16 + lrow)*LDA + lk8]);
    #pragma unroll
    for (int ni = 0; ni < 4; ++ni) {
      const int cr = ((wn*64 + ni*16 + lrow) << 2) + kg;
      const int pr = cr ^ ((cr >> 2) & 7);
      bF[ni] = *reinterpret_cast<const short8*>(&bsc[pr << 3]);
    }
    #pragma unroll
    for (int mi = 0; mi < 4; ++mi)
      #pragma unroll
      for (int ni = 0; ni < 4; ++ni)
        acc[mi][ni] = __builtin_amdgcn_mfma_f32_16x16x32_bf16(aF[mi], bF[ni], acc[mi][ni], 0, 0, 0);
    __syncthreads();
  }
  float wvv[4];
  #pragma unroll
  for (int ni = 0; ni < 4; ++ni) wvv[ni] = Wv[n0 + wn*64 + ni*16 + lrow];
  #pragma unroll
  for (int mi = 0; mi < 4; ++mi) {
    #pragma unroll
    for (int j = 0; j < 4; ++j) {
      const int row_local = wm*64 + mi*16 + g4 + j;
      const int r  = r0 + row_local;
      const int bb = r / HW_;
      const float* a2 = attn2p + (size_t)bb*ATTN_ + n0 + wn*64;
      float s = 0.f;
      #pragma unroll
      for (int ni = 0; ni < 4; ++ni) {
        float v = acc[mi][ni][j] + a2[ni*16 + lrow];
        v = fmaxf(v, 0.f);
        s = fmaf(v, wvv[ni], s);
      }
      s += __shfl_xor(s, 1);
      s += __shfl_xor(s, 2);
      s += __shfl_xor(s, 4);
      s += __shfl_xor(s, 8);
      if (lrow == 0) plog[row_local][wn] = s;
    }
  }
  __syncthreads();
  if (tid < BM)
    partials[(size_t)(r0 + tid)*4 + nb] = plog[tid][0] + plog[tid][1];
}

// ---------------- kernel 4: softmax (4 partials per s)
__global__ __launch_bounds__(64)
void k_softmax(const float* __restrict__ partials, const float* __restrict__ bvp,
               float* __restrict__ alpha) {
  const int b = blockIdx.x;
  const int t = threadIdx.x;
  const float bv = bvp[0];
  float lg[4];
  #pragma unroll
  for (int i = 0; i < 4; ++i) {
    const int s = t + i*64;
    if (s < HW_) {
      const float4 p = *reinterpret_cast<const float4*>(&partials[(size_t)(b*HW_ + s)*4]);
      lg[i] = p.x + p.y + p.z + p.w + bv;
    } else lg[i] = -INFINITY;
  }
  float mx = fmaxf(fmaxf(lg[0], lg[1]), fmaxf(lg[2], lg[3]));
  #pragma unroll
  for (int off = 32; off; off >>= 1) mx = fmaxf(mx, __shfl_xor(mx, off));
  float sum = 0.f;
  #pragma unroll
  for (int i = 0; i < 4; ++i) { lg[i] = expf(lg[i] - mx); sum += lg[i]; }
  #pragma unroll
  for (int off = 32; off; off >>= 1) sum += __shfl_xor(sum, off);
  const float inv = 1.0f / sum;
  #pragma unroll
  for (int i = 0; i < 4; ++i) {
    const int s = t + i*64;
    if (s < HW_) alpha[b*HW_ + s] = lg[i] * inv;
  }
}

// ---------------- kernel 5a: context from bf16 enc
__global__ __launch_bounds__(256)
void k_context_bf16(const unsigned short* __restrict__ ench,
                    const float* __restrict__ alpha, float* __restrict__ ctx) {
  __shared__ float al[HW_];
  const int b = blockIdx.x;
  const int t = threadIdx.x;
  if (t < HW_) al[t] = alpha[b*HW_ + t];
  __syncthreads();
  const unsigned short* base = ench + (size_t)b*HW_*ENC_ + t*8;
  float acc[8] = {0.f,0.f,0.f,0.f,0.f,0.f,0.f,0.f};
  #pragma unroll 2
  for (int s = 0; s < HW_; ++s) {
    const uint4 v = *reinterpret_cast<const uint4*>(base + (size_t)s*ENC_);
    const float a = al[s];
    const unsigned u[4] = {v.x, v.y, v.z, v.w};
    #pragma unroll
    for (int q = 0; q < 4; ++q) {
      const float lo = __builtin_bit_cast(float, u[q] << 16);
      const float hi = __builtin_bit_cast(float, u[q] & 0xffff0000u);
      acc[2*q]   = fmaf(a, lo, acc[2*q]);
      acc[2*q+1] = fmaf(a, hi, acc[2*q+1]);
    }
  }
  float4* o = reinterpret_cast<float4*>(&ctx[(size_t)b*ENC_ + t*8]);
  o[0] = make_float4(acc[0], acc[1], acc[2], acc[3]);
  o[1] = make_float4(acc[4], acc[5], acc[6], acc[7]);
}

// ---------------- kernel 5b: context from f32 enc (fallback)
__global__ __launch_bounds__(256)
void k_context_f32(const float* __restrict__ enc, const float* __restrict__ alpha,
                   float* __restrict__ ctx) {
  __shared__ float al[HW_];
  const int bi = blockIdx.x;
  const int b  = bi >> 1;
  const int e0 = (bi & 1) << 10;
  const int t  = threadIdx.x;
  if (t < HW_) al[t] = alpha[b*HW_ + t];
  __syncthreads();
  const float* base = enc + (size_t)b*HW_*ENC_ + e0 + t*4;
  float4 acc = {0.f, 0.f, 0.f, 0.f};
  #pragma unroll 4
  for (int s = 0; s < HW_; ++s) {
    const float a = al[s];
    const float4 v = *reinterpret_cast<const float4*>(base + (size_t)s*ENC_);
    acc.x = fmaf(a, v.x, acc.x);
    acc.y = fmaf(a, v.y, acc.y);
    acc.z = fmaf(a, v.z, acc.z);
    acc.w = fmaf(a, v.w, acc.w);
  }
  *reinterpret_cast<float4*>(&ctx[(size_t)b*ENC_ + e0 + t*4]) = acc;
}

// ---------------- launch
extern "C" void kernel_launch(void* const* d_in, const int* in_sizes, int n_in,
                              void* d_out, int out_size, void* d_ws, size_t ws_size,
                              hipStream_t stream) {
  const float* enc   = (const float*)d_in[0];
  const float* dec_h = (const float*)d_in[1];
  const float* Wenc  = (const float*)d_in[2];
  const float* benc  = (const float*)d_in[3];
  const float* Wdec  = (const float*)d_in[4];
  const float* bdec  = (const float*)d_in[5];
  const float* Wv    = (const float*)d_in[6];
  const float* bv    = (const float*)d_in[7];

  float* ctx   = (float*)d_out;                     // [512][2048]
  float* alpha = (float*)d_out + (size_t)B_*ENC_;   // [512][196]

  char* ws = (char*)d_ws;
  float*          attn2p   = (float*)ws;                            // 1.0 MB
  unsigned short* WencT    = (unsigned short*)(ws + (1u << 20));    // 2.0 MB
  float*          partials = (float*)(ws + 3u*(1u << 20));          // 1.6 MB [M][4]
  unsigned short* ench     = (unsigned short*)(ws + 5u*(1u << 20)); // 411 MB
  const size_t needed = 5u*(1u << 20) + (size_t)M_*ENC_*sizeof(unsigned short);
  const bool big = (ws_size >= needed);

  if (big) {
    hipLaunchKernelGGL(k_pre,       dim3(3584),            dim3(256), 0, stream,
                       enc, ench, Wenc, WencT, dec_h, Wdec, bdec, benc, attn2p);
    hipLaunchKernelGGL(k_gemm8,     dim3(1568),            dim3(512), 0, stream,
                       ench, WencT, attn2p, Wv, partials);
    hipLaunchKernelGGL(k_softmax,   dim3(B_),              dim3(64),  0, stream,
                       partials, bv, alpha);
    hipLaunchKernelGGL(k_context_bf16, dim3(B_),           dim3(256), 0, stream,
                       ench, alpha, ctx);
  } else {
    hipLaunchKernelGGL(k_attn2,     dim3(B_),                dim3(256), 0, stream,
                       dec_h, Wdec, bdec, benc, attn2p);
    hipLaunchKernelGGL(k_transpose, dim3(ENC_/32, ATTN_/32), dim3(256), 0, stream,
                       Wenc, WencT);
    hipLaunchKernelGGL(k_gemm_logits_f32, dim3(3136),      dim3(256), 0, stream,
                       enc, WencT, attn2p, Wv, partials);
    hipLaunchKernelGGL(k_softmax,   dim3(B_),              dim3(64),  0, stream,
                       partials, bv, alpha);
    hipLaunchKernelGGL(k_context_f32, dim3(1024),          dim3(256), 0, stream,
                       enc, alpha, ctx);
  }
}

// Round 17
// 650.907 us; speedup vs baseline: 1.0399x; 1.0399x over previous
//
#include <hip/hip_runtime.h>
#include <hip/hip_bf16.h>
#include <cstdint>
#include <cstddef>

#define B_    512
#define HW_   196
#define ENC_  2048
#define DEC_  512
#define ATTN_ 512
#define M_    (B_*HW_)   // 100352 = 392*256

typedef __attribute__((ext_vector_type(8))) short short8;
typedef __attribute__((ext_vector_type(4))) float f32x4;

__device__ __forceinline__ unsigned short f2bf(float x) {
  __bf16 b = (__bf16)x;
  return __builtin_bit_cast(unsigned short, b);
}
__device__ __forceinline__ unsigned int cvt2(float x, float y) {
  return (unsigned)f2bf(x) | ((unsigned)f2bf(y) << 16);
}

__device__ __forceinline__ void gload_lds16(const void* g, void* l) {
  __builtin_amdgcn_global_load_lds(
      (const __attribute__((address_space(1))) void*)g,
      (__attribute__((address_space(3))) void*)l, 16, 0, 0);
}

// ---------------- kernel 0 (fused preamble): convert | transpose | attn2
#define NCONV 2048
__global__ __launch_bounds__(256)
void k_pre(const float* __restrict__ enc, unsigned short* __restrict__ ench,
           const float* __restrict__ Wenc, unsigned short* __restrict__ WencT,
           const float* __restrict__ dec_h, const float* __restrict__ Wdec,
           const float* __restrict__ bdec, const float* __restrict__ benc,
           float* __restrict__ attn2p) {
  __shared__ float smem[32][33];
  const int bid = blockIdx.x;
  const int t   = threadIdx.x;
  if (bid < NCONV) {
    const size_t total  = (size_t)M_ * ENC_;
    const size_t stride = (size_t)NCONV * 256 * 8;
    for (size_t i = ((size_t)bid * 256 + t) * 8; i < total; i += stride) {
      const float4 a = *reinterpret_cast<const float4*>(enc + i);
      const float4 b = *reinterpret_cast<const float4*>(enc + i + 4);
      uint4 o;
      o.x = cvt2(a.x, a.y);  o.y = cvt2(a.z, a.w);
      o.z = cvt2(b.x, b.y);  o.w = cvt2(b.z, b.w);
      *reinterpret_cast<uint4*>(ench + i) = o;
    }
  } else if (bid < NCONV + 1024) {
    const int b2 = bid - NCONV;
    const int e0 = (b2 & 63) * 32;
    const int a0 = (b2 >> 6) * 32;
    const int li = t >> 5;
    const int lj = t & 31;
    #pragma unroll
    for (int rep = 0; rep < 4; ++rep) {
      const int i = li + rep*8;
      smem[i][lj] = Wenc[(size_t)(e0 + i)*ATTN_ + a0 + lj];
    }
    __syncthreads();
    #pragma unroll
    for (int rep = 0; rep < 4; ++rep) {
      const int ar = li + rep*8;
      WencT[(size_t)(a0 + ar)*ENC_ + e0 + lj] = f2bf(smem[lj][ar]);
    }
  } else {
    const int b = bid - (NCONV + 1024);
    float* dh = &smem[0][0];
    dh[t]       = dec_h[b*DEC_ + t];
    dh[t + 256] = dec_h[b*DEC_ + t + 256];
    __syncthreads();
    #pragma unroll
    for (int rep = 0; rep < 2; ++rep) {
      const int a = t + rep*256;
      float acc = bdec[a] + benc[a];
      #pragma unroll 8
      for (int k = 0; k < DEC_; ++k)
        acc = fmaf(dh[k], Wdec[(size_t)k*ATTN_ + a], acc);
      attn2p[(size_t)b*ATTN_ + a] = acc;
    }
  }
}

// ---------------- standalone attn2 / transpose (fallback path only)
__global__ __launch_bounds__(256)
void k_attn2(const float* __restrict__ dec_h, const float* __restrict__ Wdec,
             const float* __restrict__ bdec, const float* __restrict__ benc,
             float* __restrict__ attn2p) {
  __shared__ float dh[DEC_];
  const int b = blockIdx.x;
  const int t = threadIdx.x;
  dh[t]       = dec_h[b*DEC_ + t];
  dh[t + 256] = dec_h[b*DEC_ + t + 256];
  __syncthreads();
  #pragma unroll
  for (int rep = 0; rep < 2; ++rep) {
    const int a = t + rep*256;
    float acc = bdec[a] + benc[a];
    #pragma unroll 8
    for (int k = 0; k < DEC_; ++k)
      acc = fmaf(dh[k], Wdec[(size_t)k*ATTN_ + a], acc);
    attn2p[(size_t)b*ATTN_ + a] = acc;
  }
}

__global__ __launch_bounds__(256)
void k_transpose(const float* __restrict__ Wenc, unsigned short* __restrict__ WencT) {
  __shared__ float tile[32][33];
  const int e0 = blockIdx.x * 32;
  const int a0 = blockIdx.y * 32;
  const int t  = threadIdx.x;
  const int li = t >> 5;
  const int lj = t & 31;
  #pragma unroll
  for (int rep = 0; rep < 4; ++rep) {
    const int i = li + rep*8;
    tile[i][lj] = Wenc[(size_t)(e0 + i)*ATTN_ + a0 + lj];
  }
  __syncthreads();
  #pragma unroll
  for (int rep = 0; rep < 4; ++rep) {
    const int ar = li + rep*8;
    WencT[(size_t)(a0 + ar)*ENC_ + e0 + lj] = f2bf(tile[lj][ar]);
  }
}

// ---------------- kernel 3: r11 GEMM (pipe-overlap schedule) — best known
// BM=256 BN=128 BK=64, 512 thr (8 waves 4Mx2N), wave 64x64, tri-buffered LDS.
// ONE barrier + one counted vmcnt(6) per K-tile. Each window computes frag set
// for (kt,ks) while ds_read-ing the NEXT set, SGB-pinned {MFMA x4, DS_READ x2}.
#define NKT 32   // 2048/64

__global__ __launch_bounds__(512, 1)
void k_gemm8(const unsigned short* __restrict__ ench,
             const unsigned short* __restrict__ WencT,
             const float* __restrict__ attn2p,
             const float* __restrict__ Wv,
             float* __restrict__ partials) {
  __shared__ unsigned short A3[3][256*64];   // 96 KB
  __shared__ unsigned short B3[3][128*64];   // 48 KB

  const int tid = threadIdx.x;
  const int id  = blockIdx.x;
  const int xcd  = id & 7;
  const int rest = id >> 3;              // [0,196)
  const int nb   = rest & 3;
  const int mblk = (rest >> 2)*8 + xcd;  // [0,392) bijective
  const int r0 = mblk * 256;
  const int n0 = nb * 128;

  const int w  = tid >> 6;
  const int l  = tid & 63;
  const int wm = w >> 1, wn = w & 1;     // 4M x 2N
  const int lrow = l & 15;
  const int kg   = l >> 4;

  const unsigned short* aBase[2];
  #pragma unroll
  for (int i = 0; i < 2; ++i) {
    const int j  = tid + i*512;
    const int rr = j >> 3;
    const int kc = (j & 7) ^ (rr & 7);
    aBase[i] = ench + (size_t)(r0 + rr)*ENC_ + kc*8;
  }
  const unsigned short* bBase;
  {
    const int rr = tid >> 3;
    const int kc = (tid & 7) ^ (rr & 7);
    bBase = WencT + (size_t)(n0 + rr)*ENC_ + kc*8;
  }

  int aOff[2][4], bOff[2][4];
  #pragma unroll
  for (int ks = 0; ks < 2; ++ks) {
    #pragma unroll
    for (int mi = 0; mi < 4; ++mi) {
      const int row = wm*64 + mi*16 + lrow;
      aOff[ks][mi] = (row*8 + ((ks*4 + kg) ^ (row & 7))) * 8;
    }
    #pragma unroll
    for (int ni = 0; ni < 4; ++ni) {
      const int row = wn*64 + ni*16 + lrow;
      bOff[ks][ni] = (row*8 + ((ks*4 + kg) ^ (row & 7))) * 8;
    }
  }

  f32x4 acc[4][4];
  #pragma unroll
  for (int mi = 0; mi < 4; ++mi)
    #pragma unroll
    for (int ni = 0; ni < 4; ++ni)
      acc[mi][ni] = (f32x4){0.f, 0.f, 0.f, 0.f};

#define STAGE(KT, KS) do {                                                     \
    const size_t _ko = (size_t)(KT)*64;                                        \
    const int _bw = (KT) % 3;                                                  \
    gload_lds16(aBase[0] + (size_t)(KS)*(128*ENC_) + _ko,                      \
                &A3[_bw][(KS)*8192 + tid*8]);                                  \
    gload_lds16(aBase[1] + (size_t)(KS)*(128*ENC_) + _ko,                      \
                &A3[_bw][(KS)*8192 + 4096 + tid*8]);                           \
    gload_lds16(bBase    + (size_t)(KS)*(64*ENC_)  + _ko,                      \
                &B3[_bw][(KS)*4096 + tid*8]);                                  \
  } while (0)

#define MFMA16(AA, BB) do {                                                    \
    _Pragma("unroll")                                                          \
    for (int mi = 0; mi < 4; ++mi)                                             \
      _Pragma("unroll")                                                        \
      for (int ni = 0; ni < 4; ++ni)                                           \
        acc[mi][ni] = __builtin_amdgcn_mfma_f32_16x16x32_bf16(                 \
            AA[mi], BB[ni], acc[mi][ni], 0, 0, 0);                             \
  } while (0)

#define PIN8 do {                                                              \
    _Pragma("unroll")                                                          \
    for (int g = 0; g < 4; ++g) {                                              \
      __builtin_amdgcn_sched_group_barrier(0x008, 4, 0);  /* 4 MFMA   */       \
      __builtin_amdgcn_sched_group_barrier(0x100, 2, 0);  /* 2 DS_READ*/       \
    }                                                                          \
  } while (0)

#define READSET(AD, BD, BUF, KS) do {                                          \
    const unsigned short* _aB = &A3[BUF][0];                                   \
    const unsigned short* _bB = &B3[BUF][0];                                   \
    _Pragma("unroll")                                                          \
    for (int mi = 0; mi < 4; ++mi)                                             \
      AD[mi] = *reinterpret_cast<const short8*>(&_aB[aOff[KS][mi]]);           \
    _Pragma("unroll")                                                          \
    for (int ni = 0; ni < 4; ++ni)                                             \
      BD[ni] = *reinterpret_cast<const short8*>(&_bB[bOff[KS][ni]]);           \
  } while (0)

  STAGE(0, 0); STAGE(0, 1);
  STAGE(1, 0); STAGE(1, 1);
  asm volatile("s_waitcnt vmcnt(6)" ::: "memory");
  __builtin_amdgcn_s_barrier();

  short8 aX[4], bX[4], aY[4], bY[4];
  READSET(aX, bX, 0, 0);

  for (int kt = 0; kt < 30; ++kt) {
    const int bc = kt % 3;
    const int bn = (kt + 1) % 3;
    asm volatile("s_waitcnt lgkmcnt(0)" ::: "memory");
    __builtin_amdgcn_sched_barrier(0);
    __builtin_amdgcn_s_setprio(1);
    READSET(aY, bY, bc, 1);
    MFMA16(aX, bX);
    PIN8;
    __builtin_amdgcn_s_setprio(0);
    __builtin_amdgcn_sched_barrier(0);
    STAGE(kt + 2, 0);
    STAGE(kt + 2, 1);
    __builtin_amdgcn_sched_barrier(0);
    asm volatile("s_waitcnt vmcnt(6)" ::: "memory");
    __builtin_amdgcn_s_barrier();
    asm volatile("s_waitcnt lgkmcnt(0)" ::: "memory");
    __builtin_amdgcn_sched_barrier(0);
    __builtin_amdgcn_s_setprio(1);
    READSET(aX, bX, bn, 0);
    MFMA16(aY, bY);
    PIN8;
    __builtin_amdgcn_s_setprio(0);
    __builtin_amdgcn_sched_barrier(0);
  }
  {
    asm volatile("s_waitcnt lgkmcnt(0)" ::: "memory");
    __builtin_amdgcn_sched_barrier(0);
    __builtin_amdgcn_s_setprio(1);
    READSET(aY, bY, 0, 1);          // (30,1), buf 0
    MFMA16(aX, bX);
    PIN8;
    __builtin_amdgcn_s_setprio(0);
    __builtin_amdgcn_sched_barrier(0);
    asm volatile("s_waitcnt vmcnt(0)" ::: "memory");
    __builtin_amdgcn_s_barrier();
    asm volatile("s_waitcnt lgkmcnt(0)" ::: "memory");
    __builtin_amdgcn_sched_barrier(0);
    __builtin_amdgcn_s_setprio(1);
    READSET(aX, bX, 1, 0);          // (31,0), buf 1
    MFMA16(aY, bY);
    PIN8;
    __builtin_amdgcn_s_setprio(0);
    __builtin_amdgcn_sched_barrier(0);
  }
  {
    asm volatile("s_waitcnt lgkmcnt(0)" ::: "memory");
    __builtin_amdgcn_sched_barrier(0);
    __builtin_amdgcn_s_setprio(1);
    READSET(aY, bY, 1, 1);          // (31,1)
    MFMA16(aX, bX);
    PIN8;
    __builtin_amdgcn_s_setprio(0);
    asm volatile("s_waitcnt lgkmcnt(0)" ::: "memory");
    __builtin_amdgcn_sched_barrier(0);
    MFMA16(aY, bY);
  }
#undef READSET
#undef PIN8
#undef MFMA16
#undef STAGE

  __syncthreads();
  float* plog = reinterpret_cast<float*>(&A3[0][0]);   // [256][2]
  float wvv[4];
  #pragma unroll
  for (int ni = 0; ni < 4; ++ni) wvv[ni] = Wv[n0 + wn*64 + ni*16 + lrow];
  #pragma unroll
  for (int mi = 0; mi < 4; ++mi) {
    #pragma unroll
    for (int j = 0; j < 4; ++j) {
      const int row_local = wm*64 + mi*16 + kg*4 + j;
      const int r  = r0 + row_local;
      const int bb = r / HW_;
      const float* a2 = attn2p + (size_t)bb*ATTN_ + n0 + wn*64;
      float s = 0.f;
      #pragma unroll
      for (int ni = 0; ni < 4; ++ni) {
        float v = acc[mi][ni][j] + a2[ni*16 + lrow];
        v = fmaxf(v, 0.f);
        s = fmaf(v, wvv[ni], s);
      }
      s += __shfl_xor(s, 1);
      s += __shfl_xor(s, 2);
      s += __shfl_xor(s, 4);
      s += __shfl_xor(s, 8);
      if (lrow == 0) plog[row_local*2 + wn] = s;
    }
  }
  __syncthreads();
  if (tid < 256)
    partials[(size_t)(r0 + tid)*4 + nb] = plog[tid*2] + plog[tid*2 + 1];
}

// ---------------- kernel 3 (fallback, small ws): f32 reg-staged 2-phase
#define BM 128
#define BN 128
#define BK 32
#define LDA 40
#define NT (ENC_/BK)
__device__ __forceinline__ int invswz8(int p) {
  const int b2 = ((p >> 2) ^ (p >> 4)) & 1;
  const int b1 = ((p >> 1) ^ (p >> 3)) & 1;
  const int b0 = (p ^ (p >> 2) ^ (p >> 4)) & 1;
  return (p & ~7) | (b2 << 2) | (b1 << 1) | b0;
}
__global__ __launch_bounds__(256)
void k_gemm_logits_f32(const float* __restrict__ enc,
                       const unsigned short* __restrict__ WencT,
                       const float* __restrict__ attn2p,
                       const float* __restrict__ Wv,
                       float* __restrict__ partials) {
  __shared__ unsigned short As[BM*LDA];
  __shared__ unsigned short Bs[2][BN*BK];
  __shared__ float plog[BM][2];
  const int tid  = threadIdx.x;
  const int id   = blockIdx.x;
  const int xcd  = id & 7;
  const int rest = id >> 3;
  const int nb   = rest & 3;
  const int mblk = (rest >> 2) * 8 + xcd;
  const int r0 = mblk * BM;
  const int n0 = nb * BN;
  const int arow  = tid >> 1;
  const int ahalf = (tid & 1) << 4;
  const float* aptr = enc + (size_t)(r0 + arow)*ENC_ + ahalf;
  const unsigned short* bbase = WencT + (size_t)n0*ENC_;
  const int w  = tid >> 6;
  const int l  = tid & 63;
  const int wm = w >> 1, wn = w & 1;
  const int lrow = l & 15;
  const int kg   = l >> 4;
  const int lk8  = kg << 3;
  const int g4   = kg << 2;
  f32x4 acc[4][4];
  #pragma unroll
  for (int mi = 0; mi < 4; ++mi)
    #pragma unroll
    for (int ni = 0; ni < 4; ++ni)
      acc[mi][ni] = (f32x4){0.f, 0.f, 0.f, 0.f};
  float4 ar[4];
  #pragma unroll
  for (int i = 0; i < 4; ++i) ar[i] = *reinterpret_cast<const float4*>(aptr + i*4);
  #pragma unroll
  for (int r = 0; r < 2; ++r) {
    const int p = r*256 + tid;
    const int c = invswz8(p);
    gload_lds16(bbase + (size_t)(c >> 2)*ENC_ + (c & 3)*8, &Bs[0][p*8]);
  }
  for (int kt = 0; kt < NT; ++kt) {
    {
      unsigned int pk[8];
      #pragma unroll
      for (int i = 0; i < 4; ++i) {
        pk[2*i]   = cvt2(ar[i].x, ar[i].y);
        pk[2*i+1] = cvt2(ar[i].z, ar[i].w);
      }
      uint4* da = reinterpret_cast<uint4*>(&As[arow*LDA + ahalf]);
      da[0] = make_uint4(pk[0], pk[1], pk[2], pk[3]);
      da[1] = make_uint4(pk[4], pk[5], pk[6], pk[7]);
    }
    __syncthreads();
    if (kt + 1 < NT) {
      const float* ap = aptr + (kt + 1)*BK;
      #pragma unroll
      for (int i = 0; i < 4; ++i) ar[i] = *reinterpret_cast<const float4*>(ap + i*4);
      const int k0n = (kt + 1)*BK;
      unsigned short* bdst = Bs[(kt + 1) & 1];
      #pragma unroll
      for (int r = 0; r < 2; ++r) {
        const int p = r*256 + tid;
        const int c = invswz8(p);
        gload_lds16(bbase + (size_t)(c >> 2)*ENC_ + k0n + (c & 3)*8, &bdst[p*8]);
      }
    }
    const unsigned short* bsc = Bs[kt & 1];
    short8 aF[4], bF[4];
    #pragma unroll
    for (int mi = 0; mi < 4; ++mi)
      aF[mi] = *reinterpret_cast<const short8*>(&As[(wm*64 + mi*16 + lrow)*LDA + lk8]);
    #pragma unroll
    for (int ni = 0; ni < 4; ++ni) {
      const int cr = ((wn*64 + ni*16 + lrow) << 2) + kg;
      const int pr = cr ^ ((cr >> 2) & 7);
      bF[ni] = *reinterpret_cast<const short8*>(&bsc[pr << 3]);
    }
    #pragma unroll
    for (int mi = 0; mi < 4; ++mi)
      #pragma unroll
      for (int ni = 0; ni < 4; ++ni)
        acc[mi][ni] = __builtin_amdgcn_mfma_f32_16x16x32_bf16(aF[mi], bF[ni], acc[mi][ni], 0, 0, 0);
    __syncthreads();
  }
  float wvv[4];
  #pragma unroll
  for (int ni = 0; ni < 4; ++ni) wvv[ni] = Wv[n0 + wn*64 + ni*16 + lrow];
  #pragma unroll
  for (int mi = 0; mi < 4; ++mi) {
    #pragma unroll
    for (int j = 0; j < 4; ++j) {
      const int row_local = wm*64 + mi*16 + g4 + j;
      const int r  = r0 + row_local;
      const int bb = r / HW_;
      const float* a2 = attn2p + (size_t)bb*ATTN_ + n0 + wn*64;
      float s = 0.f;
      #pragma unroll
      for (int ni = 0; ni < 4; ++ni) {
        float v = acc[mi][ni][j] + a2[ni*16 + lrow];
        v = fmaxf(v, 0.f);
        s = fmaf(v, wvv[ni], s);
      }
      s += __shfl_xor(s, 1);
      s += __shfl_xor(s, 2);
      s += __shfl_xor(s, 4);
      s += __shfl_xor(s, 8);
      if (lrow == 0) plog[row_local][wn] = s;
    }
  }
  __syncthreads();
  if (tid < BM)
    partials[(size_t)(r0 + tid)*4 + nb] = plog[tid][0] + plog[tid][1];
}

// ---------------- kernel 4: softmax (4 partials per s)
__global__ __launch_bounds__(64)
void k_softmax(const float* __restrict__ partials, const float* __restrict__ bvp,
               float* __restrict__ alpha) {
  const int b = blockIdx.x;
  const int t = threadIdx.x;
  const float bv = bvp[0];
  float lg[4];
  #pragma unroll
  for (int i = 0; i < 4; ++i) {
    const int s = t + i*64;
    if (s < HW_) {
      const float4 p = *reinterpret_cast<const float4*>(&partials[(size_t)(b*HW_ + s)*4]);
      lg[i] = p.x + p.y + p.z + p.w + bv;
    } else lg[i] = -INFINITY;
  }
  float mx = fmaxf(fmaxf(lg[0], lg[1]), fmaxf(lg[2], lg[3]));
  #pragma unroll
  for (int off = 32; off; off >>= 1) mx = fmaxf(mx, __shfl_xor(mx, off));
  float sum = 0.f;
  #pragma unroll
  for (int i = 0; i < 4; ++i) { lg[i] = expf(lg[i] - mx); sum += lg[i]; }
  #pragma unroll
  for (int off = 32; off; off >>= 1) sum += __shfl_xor(sum, off);
  const float inv = 1.0f / sum;
  #pragma unroll
  for (int i = 0; i < 4; ++i) {
    const int s = t + i*64;
    if (s < HW_) alpha[b*HW_ + s] = lg[i] * inv;
  }
}

// ---------------- kernel 5a: context from bf16 enc
__global__ __launch_bounds__(256)
void k_context_bf16(const unsigned short* __restrict__ ench,
                    const float* __restrict__ alpha, float* __restrict__ ctx) {
  __shared__ float al[HW_];
  const int b = blockIdx.x;
  const int t = threadIdx.x;
  if (t < HW_) al[t] = alpha[b*HW_ + t];
  __syncthreads();
  const unsigned short* base = ench + (size_t)b*HW_*ENC_ + t*8;
  float acc[8] = {0.f,0.f,0.f,0.f,0.f,0.f,0.f,0.f};
  #pragma unroll 2
  for (int s = 0; s < HW_; ++s) {
    const uint4 v = *reinterpret_cast<const uint4*>(base + (size_t)s*ENC_);
    const float a = al[s];
    const unsigned u[4] = {v.x, v.y, v.z, v.w};
    #pragma unroll
    for (int q = 0; q < 4; ++q) {
      const float lo = __builtin_bit_cast(float, u[q] << 16);
      const float hi = __builtin_bit_cast(float, u[q] & 0xffff0000u);
      acc[2*q]   = fmaf(a, lo, acc[2*q]);
      acc[2*q+1] = fmaf(a, hi, acc[2*q+1]);
    }
  }
  float4* o = reinterpret_cast<float4*>(&ctx[(size_t)b*ENC_ + t*8]);
  o[0] = make_float4(acc[0], acc[1], acc[2], acc[3]);
  o[1] = make_float4(acc[4], acc[5], acc[6], acc[7]);
}

// ---------------- kernel 5b: context from f32 enc (fallback)
__global__ __launch_bounds__(256)
void k_context_f32(const float* __restrict__ enc, const float* __restrict__ alpha,
                   float* __restrict__ ctx) {
  __shared__ float al[HW_];
  const int bi = blockIdx.x;
  const int b  = bi >> 1;
  const int e0 = (bi & 1) << 10;
  const int t  = threadIdx.x;
  if (t < HW_) al[t] = alpha[b*HW_ + t];
  __syncthreads();
  const float* base = enc + (size_t)b*HW_*ENC_ + e0 + t*4;
  float4 acc = {0.f, 0.f, 0.f, 0.f};
  #pragma unroll 4
  for (int s = 0; s < HW_; ++s) {
    const float a = al[s];
    const float4 v = *reinterpret_cast<const float4*>(base + (size_t)s*ENC_);
    acc.x = fmaf(a, v.x, acc.x);
    acc.y = fmaf(a, v.y, acc.y);
    acc.z = fmaf(a, v.z, acc.z);
    acc.w = fmaf(a, v.w, acc.w);
  }
  *reinterpret_cast<float4*>(&ctx[(size_t)b*ENC_ + e0 + t*4]) = acc;
}

// ---------------- launch
extern "C" void kernel_launch(void* const* d_in, const int* in_sizes, int n_in,
                              void* d_out, int out_size, void* d_ws, size_t ws_size,
                              hipStream_t stream) {
  const float* enc   = (const float*)d_in[0];
  const float* dec_h = (const float*)d_in[1];
  const float* Wenc  = (const float*)d_in[2];
  const float* benc  = (const float*)d_in[3];
  const float* Wdec  = (const float*)d_in[4];
  const float* bdec  = (const float*)d_in[5];
  const float* Wv    = (const float*)d_in[6];
  const float* bv    = (const float*)d_in[7];

  float* ctx   = (float*)d_out;                     // [512][2048]
  float* alpha = (float*)d_out + (size_t)B_*ENC_;   // [512][196]

  char* ws = (char*)d_ws;
  float*          attn2p   = (float*)ws;                            // 1.0 MB
  unsigned short* WencT    = (unsigned short*)(ws + (1u << 20));    // 2.0 MB
  float*          partials = (float*)(ws + 3u*(1u << 20));          // 1.6 MB [M][4]
  unsigned short* ench     = (unsigned short*)(ws + 5u*(1u << 20)); // 411 MB
  const size_t needed = 5u*(1u << 20) + (size_t)M_*ENC_*sizeof(unsigned short);
  const bool big = (ws_size >= needed);

  if (big) {
    hipLaunchKernelGGL(k_pre,       dim3(3584),            dim3(256), 0, stream,
                       enc, ench, Wenc, WencT, dec_h, Wdec, bdec, benc, attn2p);
    hipLaunchKernelGGL(k_gemm8,     dim3(1568),            dim3(512), 0, stream,
                       ench, WencT, attn2p, Wv, partials);
    hipLaunchKernelGGL(k_softmax,   dim3(B_),              dim3(64),  0, stream,
                       partials, bv, alpha);
    hipLaunchKernelGGL(k_context_bf16, dim3(B_),           dim3(256), 0, stream,
                       ench, alpha, ctx);
  } else {
    hipLaunchKernelGGL(k_attn2,     dim3(B_),                dim3(256), 0, stream,
                       dec_h, Wdec, bdec, benc, attn2p);
    hipLaunchKernelGGL(k_transpose, dim3(ENC_/32, ATTN_/32), dim3(256), 0, stream,
                       Wenc, WencT);
    hipLaunchKernelGGL(k_gemm_logits_f32, dim3(3136),      dim3(256), 0, stream,
                       enc, WencT, attn2p, Wv, partials);
    hipLaunchKernelGGL(k_softmax,   dim3(B_),              dim3(64),  0, stream,
                       partials, bv, alpha);
    hipLaunchKernelGGL(k_context_f32, dim3(1024),          dim3(256), 0, stream,
                       enc, alpha, ctx);
  }
}